// Round 1
// baseline (1328.945 us; speedup 1.0000x reference)
//
#include <hip/hip_runtime.h>
#include <stdint.h>

// ---------- types ----------
typedef unsigned short u16;
typedef u16   u16x4 __attribute__((ext_vector_type(4)));
typedef u16   u16x8 __attribute__((ext_vector_type(8)));
typedef float f32x4 __attribute__((ext_vector_type(4)));
typedef __bf16 bf16x8 __attribute__((ext_vector_type(8)));

// ---------- constants ----------
#define BB    16
#define NN    3136
#define CC    576
#define HEADS 8
#define HD    72
#define AGN   49
#define MTOT  (BB*NN)          // 50176
#define NTOT  1728             // q|k|v fused
#define SCALE 0.1178511301977579f   // 72^-0.5

__device__ __forceinline__ u16 f2bf(float f) {
    unsigned u = __float_as_uint(f);
    return (u16)((u + 0x7fffu + ((u >> 16) & 1u)) >> 16);
}
__device__ __forceinline__ float bf2f(u16 u) {
    return __uint_as_float(((unsigned)u) << 16);
}

// ---------- cast x -> bf16 ----------
__global__ __launch_bounds__(256) void k_cast_x(const float* __restrict__ x, u16* __restrict__ xb) {
    size_t i = (size_t)blockIdx.x * 256 + threadIdx.x;   // one thread per 4 elems
    f32x4 v = *(const f32x4*)(x + i * 4);
    u16x4 o; o[0] = f2bf(v[0]); o[1] = f2bf(v[1]); o[2] = f2bf(v[2]); o[3] = f2bf(v[3]);
    *(u16x4*)(xb + i * 4) = o;
}

// ---------- pack transposed bf16 weights ----------
__global__ __launch_bounds__(256) void k_prep_w(const float* __restrict__ Wq, const float* __restrict__ Wkv,
                                                const float* __restrict__ Wp,
                                                u16* __restrict__ wbT, u16* __restrict__ wpT) {
    int idx = blockIdx.x * 256 + threadIdx.x;            // 1728*576 + 576*576 = 1327104
    if (idx < NTOT * CC) {
        int nn = idx / CC, kk = idx % CC;
        float v = (nn < CC) ? Wq[kk * CC + nn] : Wkv[kk * (2 * CC) + (nn - CC)];
        wbT[idx] = f2bf(v);
    } else {
        int j = idx - NTOT * CC;
        int nn = j / CC, kk = j % CC;
        wpT[j] = f2bf(Wp[kk * CC + nn]);
    }
}

// ---------- jax.image.resize 'linear' 7x7 -> 56x56 (half-pixel, clamped) ----------
__device__ __forceinline__ float bilerp7(const float* __restrict__ g, int oy, int ox) {
    float cy = (oy - 3.5f) * 0.125f;
    float cx = (ox - 3.5f) * 0.125f;
    float fy0 = floorf(cy), fx0 = floorf(cx);
    float ty = cy - fy0, tx = cx - fx0;
    int iy0 = (int)fy0, ix0 = (int)fx0;
    int y0 = min(6, max(0, iy0)), y1 = min(6, max(0, iy0 + 1));
    int x0 = min(6, max(0, ix0)), x1 = min(6, max(0, ix0 + 1));
    float g00 = g[y0 * 7 + x0], g01 = g[y0 * 7 + x1];
    float g10 = g[y1 * 7 + x0], g11 = g[y1 * 7 + x1];
    return (1.f - ty) * ((1.f - tx) * g00 + tx * g01) + ty * ((1.f - tx) * g10 + tx * g11);
}

// bias1[h][ag][n] = resize(an)[h,ag,y,x] + ah[h,ag,y] + aw[h,ag,x]
__global__ __launch_bounds__(256) void k_bias1(const float* __restrict__ an, const float* __restrict__ ah,
                                               const float* __restrict__ aw, float* __restrict__ b1) {
    int idx = blockIdx.x * 256 + threadIdx.x;            // 8*49*3136
    int n = idx % NN; int r = idx / NN; int ag = r % AGN; int h = r / AGN;
    int y = n / 56, x = n % 56;
    float v = bilerp7(an + (h * AGN + ag) * 49, y, x);
    b1[idx] = v + ah[(h * AGN + ag) * 56 + y] + aw[(h * AGN + ag) * 56 + x];
}

// bias2[h][n][ag] = resize(na)[h,ag,y,x] + ha[h,y,ag] + wa[h,x,ag]
__global__ __launch_bounds__(256) void k_bias2(const float* __restrict__ na, const float* __restrict__ ha,
                                               const float* __restrict__ wa, float* __restrict__ b2) {
    int idx = blockIdx.x * 256 + threadIdx.x;            // 8*3136*49
    int ag = idx % AGN; int r = idx / AGN; int n = r % NN; int h = r / NN;
    int y = n / 56, x = n % 56;
    float v = bilerp7(na + (h * AGN + ag) * 49, y, x);
    b2[idx] = v + ha[(h * 56 + y) * AGN + ag] + wa[(h * 56 + x) * AGN + ag];
}

// ---------- MFMA GEMM: A[M x 576] @ Bt[N x 576]^T,  BM=128 BN=64 BK=64, 4 waves ----------
// MODE 0: bf16 store to Cb (ldc), MODE 1: f32 store + bias to Cf (ldc)
template<int MODE>
__global__ __launch_bounds__(256) void k_gemm(const u16* __restrict__ A, const u16* __restrict__ Bt,
                                              u16* __restrict__ Cb, float* __restrict__ Cf,
                                              const float* __restrict__ bias, const int ldc) {
    __shared__ u16 Asm[128 * 64];
    __shared__ u16 Bsm[64 * 64];
    const int t = threadIdx.x, lane = t & 63, wid = t >> 6;
    const int wm = wid & 1, wn = wid >> 1;
    const int row0 = blockIdx.y * 128, col0 = blockIdx.x * 64;
    const int lr = lane & 15, lk = lane >> 4;
    f32x4 acc[4][2];
#pragma unroll
    for (int m = 0; m < 4; m++)
#pragma unroll
        for (int n2 = 0; n2 < 2; n2++) acc[m][n2] = (f32x4)0.f;

    for (int kt = 0; kt < 9; ++kt) {
        const int k0 = kt * 64;
        // stage A tile: 128 rows x 64 cols bf16, XOR-swizzled source so swizzled reads are conflict-free
#pragma unroll
        for (int it = 0; it < 4; ++it) {
            int flat = it * 256 + wid * 64 + lane;       // 16B chunk index
            int r = flat >> 3, lc = (flat & 7) ^ (r & 7);
            const u16* src = A + (size_t)(row0 + r) * CC + k0 + lc * 8;
            __builtin_amdgcn_global_load_lds((const __attribute__((address_space(1))) void*)src,
                                             (__attribute__((address_space(3))) void*)(&Asm[(it * 256 + wid * 64) * 8]),
                                             16, 0, 0);
        }
#pragma unroll
        for (int it = 0; it < 2; ++it) {
            int flat = it * 256 + wid * 64 + lane;
            int r = flat >> 3, lc = (flat & 7) ^ (r & 7);
            const u16* src = Bt + (size_t)(col0 + r) * CC + k0 + lc * 8;
            __builtin_amdgcn_global_load_lds((const __attribute__((address_space(1))) void*)src,
                                             (__attribute__((address_space(3))) void*)(&Bsm[(it * 256 + wid * 64) * 8]),
                                             16, 0, 0);
        }
        __syncthreads();
#pragma unroll
        for (int kk = 0; kk < 2; ++kk) {
            const int klocal2 = (kk * 32 + lk * 8) * 2;  // byte offset within 128B row
            bf16x8 av[4], bv[2];
#pragma unroll
            for (int m = 0; m < 4; m++) {
                int row = wm * 64 + m * 16 + lr;
                av[m] = *(const bf16x8*)((const char*)Asm + row * 128 + (klocal2 ^ ((row & 7) << 4)));
            }
#pragma unroll
            for (int n2 = 0; n2 < 2; n2++) {
                int row = wn * 32 + n2 * 16 + lr;
                bv[n2] = *(const bf16x8*)((const char*)Bsm + row * 128 + (klocal2 ^ ((row & 7) << 4)));
            }
#pragma unroll
            for (int m = 0; m < 4; m++)
#pragma unroll
                for (int n2 = 0; n2 < 2; n2++)
                    acc[m][n2] = __builtin_amdgcn_mfma_f32_16x16x32_bf16(av[m], bv[n2], acc[m][n2], 0, 0, 0);
        }
        __syncthreads();
    }
    // epilogue: D row=(lane>>4)*4+j, col=lane&15
#pragma unroll
    for (int m = 0; m < 4; m++)
#pragma unroll
        for (int n2 = 0; n2 < 2; n2++)
#pragma unroll
            for (int j = 0; j < 4; j++) {
                int rgl = row0 + wm * 64 + m * 16 + lk * 4 + j;
                int cgl = col0 + wn * 32 + n2 * 16 + lr;
                if (MODE == 0) Cb[(size_t)rgl * ldc + cgl] = f2bf(acc[m][n2][j]);
                else           Cf[(size_t)rgl * ldc + cgl] = acc[m][n2][j] + bias[cgl];
            }
}

// ---------- agent pooling: a[b][ag][c] = mean_{8x8} q ----------
__global__ __launch_bounds__(256) void k_pool(const u16* __restrict__ qkv, float* __restrict__ a_f) {
    int idx = blockIdx.x * 256 + threadIdx.x;            // 16*49*576
    int c = idx % CC; int r = idx / CC; int ag = r % AGN; int b = r / AGN;
    int p1 = ag / 7, p2 = ag % 7;
    float s = 0.f;
    for (int i = 0; i < 8; i++)
        for (int j = 0; j < 8; j++)
            s += bf2f(qkv[(size_t)(b * NN + (p1 * 8 + i) * 56 + p2 * 8 + j) * NTOT + c]);
    a_f[idx] = s * 0.015625f;
}

// ---------- stage A: agent attention (softmax over n), online, per (b,h,agent-group of 13) ----------
__global__ __launch_bounds__(256) void k_stageA(const u16* __restrict__ qkv, const float* __restrict__ a_f,
                                                const float* __restrict__ bias1, float* __restrict__ agent_v) {
    const int t = threadIdx.x;
    const int bh = blockIdx.y; const int b = bh >> 3, h = bh & 7;
    const int ag0 = blockIdx.x * 13;
    const int nag = min(13, AGN - ag0);
    __shared__ float a_s[13][72];
    __shared__ float kf[64][73];
    __shared__ float vf[64][73];
    __shared__ float sc[13][64];
    __shared__ float m_s[13], l_s[13], resc[13];
    for (int idx = t; idx < nag * 72; idx += 256) {
        int r = idx / 72, dd = idx % 72;
        a_s[r][dd] = a_f[(size_t)(b * AGN + ag0 + r) * CC + h * HD + dd] * SCALE;
    }
    if (t < nag) { m_s[t] = -1e30f; l_s[t] = 0.f; }
    float acc[5] = {0.f, 0.f, 0.f, 0.f, 0.f};
    const int d = t % 72, rg = t / 72;                   // valid for t<216
    __syncthreads();
    for (int tile = 0; tile < 49; ++tile) {
        const int n0 = tile * 64;
        for (int cidx = t; cidx < 576; cidx += 256) {    // 64 rows x 9 chunks
            int nl = cidx / 9, ch = cidx - nl * 9;
            const u16* src = qkv + (size_t)(b * NN + n0 + nl) * NTOT + CC + h * HD + ch * 8;
            u16x8 kd = *(const u16x8*)src;
            u16x8 vd = *(const u16x8*)(src + CC);
#pragma unroll
            for (int j = 0; j < 8; j++) { kf[nl][ch * 8 + j] = bf2f(kd[j]); vf[nl][ch * 8 + j] = bf2f(vd[j]); }
        }
        __syncthreads();
        for (int idx = t; idx < nag * 64; idx += 256) {
            int r = idx >> 6, col = idx & 63;
            float s = bias1[(size_t)(h * AGN + ag0 + r) * NN + n0 + col];
#pragma unroll 8
            for (int dd = 0; dd < 72; ++dd) s += a_s[r][dd] * kf[col][dd];
            sc[r][col] = s;
        }
        __syncthreads();
        if (t < nag) {
            float mold = m_s[t], mt = mold;
#pragma unroll 8
            for (int c2 = 0; c2 < 64; c2++) mt = fmaxf(mt, sc[t][c2]);
            float rs = __expf(mold - mt);
            float lsum = l_s[t] * rs;
#pragma unroll 8
            for (int c2 = 0; c2 < 64; c2++) { float p = __expf(sc[t][c2] - mt); sc[t][c2] = p; lsum += p; }
            m_s[t] = mt; l_s[t] = lsum; resc[t] = rs;
        }
        __syncthreads();
        if (t < 216) {
#pragma unroll
            for (int rr = 0; rr < 5; ++rr) {
                int r = rg * 5 + rr;
                if (r < nag) {
                    float a2 = acc[rr] * resc[r];
#pragma unroll 8
                    for (int col = 0; col < 64; ++col) a2 += sc[r][col] * vf[col][d];
                    acc[rr] = a2;
                }
            }
        }
        __syncthreads();
    }
    if (t < 216) {
#pragma unroll
        for (int rr = 0; rr < 5; ++rr) {
            int r = rg * 5 + rr;
            if (r < nag) agent_v[(size_t)(bh * AGN + ag0 + r) * HD + d] = acc[rr] / l_s[r];
        }
    }
}

// ---------- stage B: per-token softmax over 49 agents + PV ----------
__global__ __launch_bounds__(256) void k_stageB(const u16* __restrict__ qkv, const float* __restrict__ a_f,
                                                const float* __restrict__ agent_v, const float* __restrict__ bias2,
                                                float* __restrict__ outatt) {
    const int t = threadIdx.x;
    const int bh = blockIdx.y; const int b = bh >> 3, h = bh & 7;
    __shared__ float a_s[49][72];
    __shared__ float av[49][72];
    for (int idx = t; idx < 49 * 72; idx += 256) {
        int ag = idx / 72, dd = idx % 72;
        a_s[ag][dd] = a_f[(size_t)(b * AGN + ag) * CC + h * HD + dd] * SCALE;
        av[ag][dd]  = agent_v[(size_t)(bh * AGN + ag) * HD + dd];
    }
    __syncthreads();
    const int n = blockIdx.x * 256 + t;
    if (n >= NN) return;
    const u16* qp = qkv + (size_t)(b * NN + n) * NTOT + h * HD;
    const float* brow = bias2 + ((size_t)h * NN + n) * AGN;
    float s[49];
#pragma unroll
    for (int ag = 0; ag < 49; ++ag) s[ag] = brow[ag];
    for (int ch = 0; ch < 9; ++ch) {                     // rolled: LDS addr runtime is fine
        u16x8 qc = *(const u16x8*)(qp + ch * 8);
        float qf[8];
#pragma unroll
        for (int j = 0; j < 8; j++) qf[j] = bf2f(qc[j]);
#pragma unroll
        for (int ag = 0; ag < 49; ++ag) {
            float a2 = s[ag];
#pragma unroll
            for (int j = 0; j < 8; j++) a2 += qf[j] * a_s[ag][ch * 8 + j];
            s[ag] = a2;
        }
    }
    float mx = -1e30f;
#pragma unroll
    for (int ag = 0; ag < 49; ++ag) mx = fmaxf(mx, s[ag]);
    float l = 0.f;
#pragma unroll
    for (int ag = 0; ag < 49; ++ag) { float p = __expf(s[ag] - mx); s[ag] = p; l += p; }
    float inv = 1.f / l;
#pragma unroll
    for (int ag = 0; ag < 49; ++ag) s[ag] *= inv;
    float* op = outatt + (size_t)(b * NN + n) * CC + h * HD;
    for (int dc = 0; dc < 9; ++dc) {
        float o8[8] = {0.f, 0.f, 0.f, 0.f, 0.f, 0.f, 0.f, 0.f};
#pragma unroll
        for (int ag = 0; ag < 49; ++ag)
#pragma unroll
            for (int j = 0; j < 8; j++) o8[j] += s[ag] * av[ag][dc * 8 + j];
#pragma unroll
        for (int j = 0; j < 8; j++) op[dc * 8 + j] = o8[j];
    }
}

// ---------- depthwise 3x3 conv + affine + relu, fused add with out_att, emit bf16 'pre' ----------
__global__ __launch_bounds__(256) void k_conv(const u16* __restrict__ qkv, const float* __restrict__ outatt,
                                              const float* __restrict__ w, const float* __restrict__ gamma,
                                              const float* __restrict__ beta, u16* __restrict__ pre) {
    int idx = blockIdx.x * 256 + threadIdx.x;            // 16*3136*144
    int c4 = idx % 144; int rest = idx / 144; int n = rest % NN; int b = rest / NN;
    int y = n / 56, x = n % 56;
    int c0 = c4 * 4;
    float a0 = 0.f, a1 = 0.f, a2 = 0.f, a3 = 0.f;
#pragma unroll
    for (int dy = -1; dy <= 1; ++dy) {
        int yy = y + dy; if (yy < 0 || yy > 55) continue;
#pragma unroll
        for (int dx = -1; dx <= 1; ++dx) {
            int xx = x + dx; if (xx < 0 || xx > 55) continue;
            const u16* vp = qkv + (size_t)(b * NN + yy * 56 + xx) * NTOT + 2 * CC + c0;
            u16x4 vv = *(const u16x4*)vp;
            int tap = (dy + 1) * 3 + (dx + 1);
            a0 += bf2f(vv[0]) * w[(c0 + 0) * 9 + tap];
            a1 += bf2f(vv[1]) * w[(c0 + 1) * 9 + tap];
            a2 += bf2f(vv[2]) * w[(c0 + 2) * 9 + tap];
            a3 += bf2f(vv[3]) * w[(c0 + 3) * 9 + tap];
        }
    }
    const float* oa = outatt + (size_t)(b * NN + n) * CC + c0;
    f32x4 o = *(const f32x4*)oa;
    float y0 = fmaxf(a0 * gamma[c0 + 0] + beta[c0 + 0], 0.f);
    float y1 = fmaxf(a1 * gamma[c0 + 1] + beta[c0 + 1], 0.f);
    float y2 = fmaxf(a2 * gamma[c0 + 2] + beta[c0 + 2], 0.f);
    float y3 = fmaxf(a3 * gamma[c0 + 3] + beta[c0 + 3], 0.f);
    u16x4 r; r[0] = f2bf(o[0] + y0); r[1] = f2bf(o[1] + y1); r[2] = f2bf(o[2] + y2); r[3] = f2bf(o[3] + y3);
    *(u16x4*)(pre + (size_t)(b * NN + n) * CC + c0) = r;
}

// ---------- launch ----------
extern "C" void kernel_launch(void* const* d_in, const int* in_sizes, int n_in,
                              void* d_out, int out_size, void* d_ws, size_t ws_size,
                              hipStream_t stream) {
    const float* x     = (const float*)d_in[0];
    const float* Wq    = (const float*)d_in[1];
    const float* Wkv   = (const float*)d_in[2];
    const float* an_b  = (const float*)d_in[3];
    const float* na_b  = (const float*)d_in[4];
    const float* ah_b  = (const float*)d_in[5];
    const float* aw_b  = (const float*)d_in[6];
    const float* ha_b  = (const float*)d_in[7];
    const float* wa_b  = (const float*)d_in[8];
    const float* dwcw  = (const float*)d_in[9];
    const float* gam   = (const float*)d_in[10];
    const float* bet   = (const float*)d_in[11];
    const float* projw = (const float*)d_in[12];
    const float* projb = (const float*)d_in[13];
    float* out = (float*)d_out;

    char* ws = (char*)d_ws;                              // needs ~248 MB
    u16* wbT  = (u16*)(ws + 0);                          // 1,990,656 B
    u16* wpT  = (u16*)(ws + 1990656);                    //   663,552 B
    u16* xb   = (u16*)(ws + 2654208);                    // 57,802,752 B (reused as 'pre' after GEMM1)
    u16* qkv  = (u16*)(ws + 60456960);                   // 173,408,256 B
    float* af = (float*)(ws + 233865216);                // 1,806,336 B
    float* agv= (float*)(ws + 235671552);                // 1,806,336 B
    float* b1 = (float*)(ws + 237477888);                // 4,917,248 B
    float* b2 = (float*)(ws + 242395136);                // 4,917,248 B

    k_cast_x<<<28224, 256, 0, stream>>>(x, xb);
    k_prep_w<<<5184, 256, 0, stream>>>(Wq, Wkv, projw, wbT, wpT);
    k_bias1<<<4802, 256, 0, stream>>>(an_b, ah_b, aw_b, b1);
    k_bias2<<<4802, 256, 0, stream>>>(na_b, ha_b, wa_b, b2);
    k_gemm<0><<<dim3(27, 392), 256, 0, stream>>>(xb, wbT, qkv, nullptr, nullptr, NTOT);
    k_pool<<<1764, 256, 0, stream>>>(qkv, af);
    k_stageA<<<dim3(4, 128), 256, 0, stream>>>(qkv, af, b1, agv);
    k_stageB<<<dim3(13, 128), 256, 0, stream>>>(qkv, af, agv, b2, out);
    k_conv<<<28224, 256, 0, stream>>>(qkv, out, dwcw, gam, bet, xb /*pre*/);
    k_gemm<1><<<dim3(9, 392), 256, 0, stream>>>(xb /*pre*/, wpT, nullptr, out, projb, CC);
}

// Round 2
// 1294.859 us; speedup vs baseline: 1.0263x; 1.0263x over previous
//
#include <hip/hip_runtime.h>
#include <stdint.h>

// ---------- types ----------
typedef unsigned short u16;
typedef u16   u16x4 __attribute__((ext_vector_type(4)));
typedef u16   u16x8 __attribute__((ext_vector_type(8)));
typedef float f32x4 __attribute__((ext_vector_type(4)));
typedef __bf16 bf16x8 __attribute__((ext_vector_type(8)));

// ---------- constants ----------
#define BB    16
#define NN    3136
#define CC    576
#define HEADS 8
#define HD    72
#define AGN   49
#define NTOT  1728
#define SCALE 0.1178511301977579f   // 72^-0.5

__device__ __forceinline__ u16 f2bf(float f) {
    unsigned u = __float_as_uint(f);
    return (u16)((u + 0x7fffu + ((u >> 16) & 1u)) >> 16);
}
__device__ __forceinline__ float bf2f(u16 u) {
    return __uint_as_float(((unsigned)u) << 16);
}

// ---------- cast x -> bf16 ----------
__global__ __launch_bounds__(256) void k_cast_x(const float* __restrict__ x, u16* __restrict__ xb) {
    size_t i = (size_t)blockIdx.x * 256 + threadIdx.x;
    f32x4 v = *(const f32x4*)(x + i * 4);
    u16x4 o; o[0] = f2bf(v[0]); o[1] = f2bf(v[1]); o[2] = f2bf(v[2]); o[3] = f2bf(v[3]);
    *(u16x4*)(xb + i * 4) = o;
}

// ---------- pack transposed bf16 weights ----------
__global__ __launch_bounds__(256) void k_prep_w(const float* __restrict__ Wq, const float* __restrict__ Wkv,
                                                const float* __restrict__ Wp,
                                                u16* __restrict__ wbT, u16* __restrict__ wpT) {
    int idx = blockIdx.x * 256 + threadIdx.x;
    if (idx < NTOT * CC) {
        int nn = idx / CC, kk = idx % CC;
        float v = (nn < CC) ? Wq[kk * CC + nn] : Wkv[kk * (2 * CC) + (nn - CC)];
        wbT[idx] = f2bf(v);
    } else {
        int j = idx - NTOT * CC;
        int nn = j / CC, kk = j % CC;
        wpT[j] = f2bf(Wp[kk * CC + nn]);
    }
}

// ---------- jax.image.resize 'linear' 7x7 -> 56x56 ----------
__device__ __forceinline__ float bilerp7(const float* __restrict__ g, int oy, int ox) {
    float cy = (oy - 3.5f) * 0.125f;
    float cx = (ox - 3.5f) * 0.125f;
    float fy0 = floorf(cy), fx0 = floorf(cx);
    float ty = cy - fy0, tx = cx - fx0;
    int iy0 = (int)fy0, ix0 = (int)fx0;
    int y0 = min(6, max(0, iy0)), y1 = min(6, max(0, iy0 + 1));
    int x0 = min(6, max(0, ix0)), x1 = min(6, max(0, ix0 + 1));
    float g00 = g[y0 * 7 + x0], g01 = g[y0 * 7 + x1];
    float g10 = g[y1 * 7 + x0], g11 = g[y1 * 7 + x1];
    return (1.f - ty) * ((1.f - tx) * g00 + tx * g01) + ty * ((1.f - tx) * g10 + tx * g11);
}

__global__ __launch_bounds__(256) void k_bias1(const float* __restrict__ an, const float* __restrict__ ah,
                                               const float* __restrict__ aw, float* __restrict__ b1) {
    int idx = blockIdx.x * 256 + threadIdx.x;
    int n = idx % NN; int r = idx / NN; int ag = r % AGN; int h = r / AGN;
    int y = n / 56, x = n % 56;
    float v = bilerp7(an + (h * AGN + ag) * 49, y, x);
    b1[idx] = v + ah[(h * AGN + ag) * 56 + y] + aw[(h * AGN + ag) * 56 + x];
}

__global__ __launch_bounds__(256) void k_bias2(const float* __restrict__ na, const float* __restrict__ ha,
                                               const float* __restrict__ wa, float* __restrict__ b2) {
    int idx = blockIdx.x * 256 + threadIdx.x;
    int ag = idx % AGN; int r = idx / AGN; int n = r % NN; int h = r / NN;
    int y = n / 56, x = n % 56;
    float v = bilerp7(na + (h * AGN + ag) * 49, y, x);
    b2[idx] = v + ha[(h * 56 + y) * AGN + ag] + wa[(h * 56 + x) * AGN + ag];
}

// ---------- MFMA GEMM: A[M x 576] @ Bt[N x 576]^T,  BM=128 BN=64 BK=64 ----------
// MODE 0: scatter bf16 to head-planar Qp/Kp/Vp;  MODE 1: f32 + bias to Cf (ldc=576)
template<int MODE>
__global__ __launch_bounds__(256) void k_gemm(const u16* __restrict__ A, const u16* __restrict__ Bt,
                                              u16* __restrict__ Qp, u16* __restrict__ Kp, u16* __restrict__ Vp,
                                              float* __restrict__ Cf, const float* __restrict__ bias) {
    __shared__ u16 Asm[128 * 64];
    __shared__ u16 Bsm[64 * 64];
    const int t = threadIdx.x, lane = t & 63, wid = t >> 6;
    const int wm = wid & 1, wn = wid >> 1;
    const int row0 = blockIdx.y * 128, col0 = blockIdx.x * 64;
    const int lr = lane & 15, lk = lane >> 4;
    f32x4 acc[4][2];
#pragma unroll
    for (int m = 0; m < 4; m++)
#pragma unroll
        for (int n2 = 0; n2 < 2; n2++) acc[m][n2] = (f32x4)0.f;

    for (int kt = 0; kt < 9; ++kt) {
        const int k0 = kt * 64;
#pragma unroll
        for (int it = 0; it < 4; ++it) {
            int flat = it * 256 + wid * 64 + lane;
            int r = flat >> 3, lc = (flat & 7) ^ (r & 7);
            const u16* src = A + (size_t)(row0 + r) * CC + k0 + lc * 8;
            __builtin_amdgcn_global_load_lds((const __attribute__((address_space(1))) void*)src,
                                             (__attribute__((address_space(3))) void*)(&Asm[(it * 256 + wid * 64) * 8]),
                                             16, 0, 0);
        }
#pragma unroll
        for (int it = 0; it < 2; ++it) {
            int flat = it * 256 + wid * 64 + lane;
            int r = flat >> 3, lc = (flat & 7) ^ (r & 7);
            const u16* src = Bt + (size_t)(col0 + r) * CC + k0 + lc * 8;
            __builtin_amdgcn_global_load_lds((const __attribute__((address_space(1))) void*)src,
                                             (__attribute__((address_space(3))) void*)(&Bsm[(it * 256 + wid * 64) * 8]),
                                             16, 0, 0);
        }
        __syncthreads();
#pragma unroll
        for (int kk = 0; kk < 2; ++kk) {
            const int klocal2 = (kk * 32 + lk * 8) * 2;
            bf16x8 av[4], bv[2];
#pragma unroll
            for (int m = 0; m < 4; m++) {
                int row = wm * 64 + m * 16 + lr;
                av[m] = *(const bf16x8*)((const char*)Asm + row * 128 + (klocal2 ^ ((row & 7) << 4)));
            }
#pragma unroll
            for (int n2 = 0; n2 < 2; n2++) {
                int row = wn * 32 + n2 * 16 + lr;
                bv[n2] = *(const bf16x8*)((const char*)Bsm + row * 128 + (klocal2 ^ ((row & 7) << 4)));
            }
#pragma unroll
            for (int m = 0; m < 4; m++)
#pragma unroll
                for (int n2 = 0; n2 < 2; n2++)
                    acc[m][n2] = __builtin_amdgcn_mfma_f32_16x16x32_bf16(av[m], bv[n2], acc[m][n2], 0, 0, 0);
        }
        __syncthreads();
    }
#pragma unroll
    for (int n2 = 0; n2 < 2; n2++) {
        int cgl = col0 + wn * 32 + n2 * 16 + lr;
        if (MODE == 0) {
            int which = cgl / 576;
            int rem = cgl - which * 576;
            int hh = rem / 72;
            int dd = rem - hh * 72;
            u16* dst = which == 0 ? Qp : (which == 1 ? Kp : Vp);
#pragma unroll
            for (int m = 0; m < 4; m++)
#pragma unroll
                for (int j = 0; j < 4; j++) {
                    int rgl = row0 + wm * 64 + m * 16 + lk * 4 + j;
                    int b = rgl / NN, n = rgl - b * NN;
                    dst[((size_t)(b * 8 + hh) * NN + n) * 72 + dd] = f2bf(acc[m][n2][j]);
                }
        } else {
#pragma unroll
            for (int m = 0; m < 4; m++)
#pragma unroll
                for (int j = 0; j < 4; j++) {
                    int rgl = row0 + wm * 64 + m * 16 + lk * 4 + j;
                    Cf[(size_t)rgl * 576 + cgl] = acc[m][n2][j] + bias[cgl];
                }
        }
    }
}

// ---------- agent pooling (head-planar q): a[b][ag][c] ----------
__global__ __launch_bounds__(256) void k_pool(const u16* __restrict__ Qp, float* __restrict__ a_f) {
    int idx = blockIdx.x * 256 + threadIdx.x;            // 16*49*576
    int c = idx % CC; int r = idx / CC; int ag = r % AGN; int b = r / AGN;
    int hh = c / 72, dd = c - hh * 72;
    int p1 = ag / 7, p2 = ag % 7;
    const u16* base = Qp + ((size_t)(b * 8 + hh) * NN) * 72 + dd;
    float s = 0.f;
    for (int i = 0; i < 8; i++)
        for (int j = 0; j < 8; j++)
            s += bf2f(base[(size_t)((p1 * 8 + i) * 56 + p2 * 8 + j) * 72]);
    a_f[idx] = s * 0.015625f;
}

// ---------- stage A: chunked flash over n, full-wave col ownership ----------
__global__ __launch_bounds__(256) void k_stageA(const u16* __restrict__ Kp, const u16* __restrict__ Vp,
                                                const float* __restrict__ a_f, const float* __restrict__ bias1,
                                                float* __restrict__ part) {
    const int t = threadIdx.x, lane = t & 63, w = t >> 6;
    const int bh = blockIdx.y, b = bh >> 3, h = bh & 7;
    const int chunk = blockIdx.x;                        // 0..6, 448 tokens each
    __shared__ float a_s[49][72];
    __shared__ float kf[64][65];
    __shared__ u16   vfs[64][80];
    __shared__ float sc[49][64];
    __shared__ float m_s[49], l_s[49], rs_s[49];

    for (int idx = t; idx < 49 * 72; idx += 256) {
        int r = idx / 72, dd = idx - r * 72;
        a_s[r][dd] = a_f[(size_t)(b * 49 + r) * CC + h * 72 + dd] * SCALE;
    }
    if (t < 49) { m_s[t] = -1e30f; l_s[t] = 0.f; }
    float acc[4][4];
#pragma unroll
    for (int p = 0; p < 4; p++)
#pragma unroll
        for (int r = 0; r < 4; r++) acc[p][r] = 0.f;
    __syncthreads();

    const size_t kvbase = ((size_t)(b * 8 + h) * NN + chunk * 448) * 72;
    for (int tile = 0; tile < 7; ++tile) {
        const int n0 = chunk * 448 + tile * 64;
        const u16* kb = Kp + kvbase + (size_t)tile * 64 * 72;
        const u16* vb = Vp + kvbase + (size_t)tile * 64 * 72;
        // stage K (f32, stride 65) + V (bf16, stride 80); global side fully contiguous
        for (int idx = t; idx < 576; idx += 256) {
            int nl = idx / 9, ch = idx - nl * 9;
            u16x8 kd = *(const u16x8*)(kb + idx * 8);
            u16x8 vd = *(const u16x8*)(vb + idx * 8);
#pragma unroll
            for (int j = 0; j < 8; j++) kf[nl][ch * 8 + j] = bf2f(kd[j]);
            *(u16x8*)&vfs[nl][ch * 8] = vd;
        }
        __syncthreads();
        // scores + online softmax: wave w owns groups gg = 4g+w (4 rows each)
#pragma unroll
        for (int g = 0; g < 4; ++g) {
            int gg = g * 4 + w;
            if (gg > 12) break;
            int rb = gg * 4;
            int rc[4]; float sv[4];
#pragma unroll
            for (int r = 0; r < 4; r++) {
                rc[r] = min(rb + r, 48);
                int brow = min(h * 49 + rb + r, 391);
                sv[r] = bias1[(size_t)brow * NN + n0 + lane];
            }
#pragma unroll 6
            for (int dq = 0; dq < 18; ++dq) {
                float k0 = kf[lane][dq * 4 + 0];
                float k1 = kf[lane][dq * 4 + 1];
                float k2 = kf[lane][dq * 4 + 2];
                float k3 = kf[lane][dq * 4 + 3];
#pragma unroll
                for (int r = 0; r < 4; r++) {
                    f32x4 a4 = *(const f32x4*)&a_s[rc[r]][dq * 4];
                    sv[r] += k0 * a4[0] + k1 * a4[1] + k2 * a4[2] + k3 * a4[3];
                }
            }
#pragma unroll
            for (int r = 0; r < 4; r++) {
                int row = rb + r;
                float s = sv[r];
                float mt = s;
#pragma unroll
                for (int xm = 1; xm <= 32; xm <<= 1) mt = fmaxf(mt, __shfl_xor(mt, xm, 64));
                float mold = m_s[rc[r]];
                float mnew = fmaxf(mold, mt);
                float p = __expf(s - mnew);
                float ps = p;
#pragma unroll
                for (int xm = 1; xm <= 32; xm <<= 1) ps += __shfl_xor(ps, xm, 64);
                if (row < 49) {
                    sc[row][lane] = p;
                    if (lane == 0) {
                        float rsc = __expf(mold - mnew);
                        rs_s[row] = rsc;
                        l_s[row] = l_s[row] * rsc + ps;
                        m_s[row] = mnew;
                    }
                }
            }
        }
        __syncthreads();
        // PV: thread owns (rowgrp-of-4, d) pairs
#pragma unroll
        for (int p = 0; p < 4; p++) {
            int idx = t + p * 256;
            if (idx < 936) {
                int rg = idx / 72, d = idx - rg * 72;
                int rb2 = rg * 4;
                int rcl[4]; float ar[4];
#pragma unroll
                for (int r = 0; r < 4; r++) { rcl[r] = min(rb2 + r, 48); ar[r] = acc[p][r] * rs_s[rcl[r]]; }
                for (int cq = 0; cq < 16; ++cq) {
                    f32x4 s4[4];
#pragma unroll
                    for (int r = 0; r < 4; r++) s4[r] = *(const f32x4*)&sc[rcl[r]][cq * 4];
#pragma unroll
                    for (int j = 0; j < 4; j++) {
                        float vv = bf2f(vfs[cq * 4 + j][d]);
#pragma unroll
                        for (int r = 0; r < 4; r++) ar[r] += s4[r][j] * vv;
                    }
                }
#pragma unroll
                for (int r = 0; r < 4; r++) acc[p][r] = ar[r];
            }
        }
        __syncthreads();
    }
    const size_t pbase = (size_t)(bh * 7 + chunk) * (49 * 74);
#pragma unroll
    for (int p = 0; p < 4; p++) {
        int idx = t + p * 256;
        if (idx < 936) {
            int rg = idx / 72, d = idx - rg * 72;
#pragma unroll
            for (int r = 0; r < 4; r++) {
                int row = rg * 4 + r;
                if (row < 49) part[pbase + row * 74 + d] = acc[p][r];
            }
        }
    }
    if (t < 49) {
        part[pbase + t * 74 + 72] = m_s[t];
        part[pbase + t * 74 + 73] = l_s[t];
    }
}

// ---------- reduce partials across 7 chunks ----------
__global__ __launch_bounds__(256) void k_reduceA(const float* __restrict__ part, float* __restrict__ agv) {
    const int bh = blockIdx.x, t = threadIdx.x;
    const float* pb = part + (size_t)bh * 7 * (49 * 74);
    for (int idx = t; idx < 49 * 72; idx += 256) {
        int row = idx / 72, d = idx - row * 72;
        float m = -1e30f;
#pragma unroll
        for (int c = 0; c < 7; c++) m = fmaxf(m, pb[c * (49 * 74) + row * 74 + 72]);
        float accv = 0.f, l = 0.f;
#pragma unroll
        for (int c = 0; c < 7; c++) {
            const float* pc = pb + c * (49 * 74) + row * 74;
            float e = __expf(pc[72] - m);
            accv += pc[d] * e;
            l += pc[73] * e;
        }
        agv[(size_t)(bh * 49 + row) * 72 + d] = accv / l;
    }
}

// ---------- stage B: per-token softmax over 49 agents + PV ----------
__global__ __launch_bounds__(256) void k_stageB(const u16* __restrict__ Qp, const float* __restrict__ a_f,
                                                const float* __restrict__ agent_v, const float* __restrict__ bias2,
                                                float* __restrict__ outatt) {
    const int t = threadIdx.x;
    const int bh = blockIdx.y; const int b = bh >> 3, h = bh & 7;
    __shared__ float a_s[49][72];
    __shared__ float av[49][72];
    for (int idx = t; idx < 49 * 72; idx += 256) {
        int ag = idx / 72, dd = idx % 72;
        a_s[ag][dd] = a_f[(size_t)(b * AGN + ag) * CC + h * HD + dd] * SCALE;
        av[ag][dd]  = agent_v[(size_t)(bh * AGN + ag) * HD + dd];
    }
    __syncthreads();
    const int n = blockIdx.x * 256 + t;
    if (n >= NN) return;
    const u16* qp = Qp + ((size_t)(b * 8 + h) * NN + n) * 72;
    const float* brow = bias2 + ((size_t)h * NN + n) * AGN;
    float s[49];
#pragma unroll
    for (int ag = 0; ag < 49; ++ag) s[ag] = brow[ag];
    for (int ch = 0; ch < 9; ++ch) {
        u16x8 qc = *(const u16x8*)(qp + ch * 8);
        float qf[8];
#pragma unroll
        for (int j = 0; j < 8; j++) qf[j] = bf2f(qc[j]);
#pragma unroll
        for (int ag = 0; ag < 49; ++ag) {
            float a2 = s[ag];
#pragma unroll
            for (int j = 0; j < 8; j++) a2 += qf[j] * a_s[ag][ch * 8 + j];
            s[ag] = a2;
        }
    }
    float mx = -1e30f;
#pragma unroll
    for (int ag = 0; ag < 49; ++ag) mx = fmaxf(mx, s[ag]);
    float l = 0.f;
#pragma unroll
    for (int ag = 0; ag < 49; ++ag) { float p = __expf(s[ag] - mx); s[ag] = p; l += p; }
    float inv = 1.f / l;
#pragma unroll
    for (int ag = 0; ag < 49; ++ag) s[ag] *= inv;
    float* op = outatt + (size_t)(b * NN + n) * CC + h * HD;
    for (int dc = 0; dc < 9; ++dc) {
        float o8[8] = {0.f, 0.f, 0.f, 0.f, 0.f, 0.f, 0.f, 0.f};
#pragma unroll
        for (int ag = 0; ag < 49; ++ag)
#pragma unroll
            for (int j = 0; j < 8; j++) o8[j] += s[ag] * av[ag][dc * 8 + j];
#pragma unroll
        for (int j = 0; j < 8; j++) op[dc * 8 + j] = o8[j];
    }
}

// ---------- depthwise 3x3 conv + affine + relu + add, emit bf16 'pre' ----------
__global__ __launch_bounds__(256) void k_conv(const u16* __restrict__ Vp, const float* __restrict__ outatt,
                                              const float* __restrict__ w, const float* __restrict__ gamma,
                                              const float* __restrict__ beta, u16* __restrict__ pre) {
    int idx = blockIdx.x * 256 + threadIdx.x;            // 16*3136*144
    int c4 = idx % 144; int rest = idx / 144; int n = rest % NN; int b = rest / NN;
    int y = n / 56, x = n % 56;
    int c0 = c4 * 4;
    int hh = c0 / 72, dl = c0 - hh * 72;
    const u16* vbase = Vp + ((size_t)(b * 8 + hh) * NN) * 72 + dl;
    float a0 = 0.f, a1 = 0.f, a2 = 0.f, a3 = 0.f;
#pragma unroll
    for (int dy = -1; dy <= 1; ++dy) {
        int yy = y + dy; if (yy < 0 || yy > 55) continue;
#pragma unroll
        for (int dx = -1; dx <= 1; ++dx) {
            int xx = x + dx; if (xx < 0 || xx > 55) continue;
            u16x4 vv = *(const u16x4*)(vbase + (size_t)(yy * 56 + xx) * 72);
            int tap = (dy + 1) * 3 + (dx + 1);
            a0 += bf2f(vv[0]) * w[(c0 + 0) * 9 + tap];
            a1 += bf2f(vv[1]) * w[(c0 + 1) * 9 + tap];
            a2 += bf2f(vv[2]) * w[(c0 + 2) * 9 + tap];
            a3 += bf2f(vv[3]) * w[(c0 + 3) * 9 + tap];
        }
    }
    const float* oa = outatt + (size_t)(b * NN + n) * CC + c0;
    f32x4 o = *(const f32x4*)oa;
    float y0 = fmaxf(a0 * gamma[c0 + 0] + beta[c0 + 0], 0.f);
    float y1 = fmaxf(a1 * gamma[c0 + 1] + beta[c0 + 1], 0.f);
    float y2 = fmaxf(a2 * gamma[c0 + 2] + beta[c0 + 2], 0.f);
    float y3 = fmaxf(a3 * gamma[c0 + 3] + beta[c0 + 3], 0.f);
    u16x4 rr; rr[0] = f2bf(o[0] + y0); rr[1] = f2bf(o[1] + y1); rr[2] = f2bf(o[2] + y2); rr[3] = f2bf(o[3] + y3);
    *(u16x4*)(pre + (size_t)(b * NN + n) * CC + c0) = rr;
}

// ---------- launch ----------
extern "C" void kernel_launch(void* const* d_in, const int* in_sizes, int n_in,
                              void* d_out, int out_size, void* d_ws, size_t ws_size,
                              hipStream_t stream) {
    const float* x     = (const float*)d_in[0];
    const float* Wq    = (const float*)d_in[1];
    const float* Wkv   = (const float*)d_in[2];
    const float* an_b  = (const float*)d_in[3];
    const float* na_b  = (const float*)d_in[4];
    const float* ah_b  = (const float*)d_in[5];
    const float* aw_b  = (const float*)d_in[6];
    const float* ha_b  = (const float*)d_in[7];
    const float* wa_b  = (const float*)d_in[8];
    const float* dwcw  = (const float*)d_in[9];
    const float* gam   = (const float*)d_in[10];
    const float* bet   = (const float*)d_in[11];
    const float* projw = (const float*)d_in[12];
    const float* projb = (const float*)d_in[13];
    float* out = (float*)d_out;

    char* ws = (char*)d_ws;
    u16* wbT  = (u16*)(ws + 0);                          //  1,990,656
    u16* wpT  = (u16*)(ws + 1990656);                    //    663,552
    u16* xb   = (u16*)(ws + 2654208);                    // 57,802,752 (reused: stageA partials, then 'pre')
    u16* Qp   = (u16*)(ws + 60456960);                   // 57,802,752
    u16* Kp   = (u16*)(ws + 118259712);                  // 57,802,752
    u16* Vp   = (u16*)(ws + 176062464);                  // 57,802,752
    float* af = (float*)(ws + 233865216);                //  1,806,336
    float* agv= (float*)(ws + 235671552);                //  1,806,336
    float* b1 = (float*)(ws + 237477888);                //  4,917,248
    float* b2 = (float*)(ws + 242395136);                //  4,917,248
    float* part = (float*)xb;                            // 12,995,584 (inside xb region)

    k_cast_x<<<28224, 256, 0, stream>>>(x, xb);
    k_prep_w<<<5184, 256, 0, stream>>>(Wq, Wkv, projw, wbT, wpT);
    k_bias1<<<4802, 256, 0, stream>>>(an_b, ah_b, aw_b, b1);
    k_bias2<<<4802, 256, 0, stream>>>(na_b, ha_b, wa_b, b2);
    k_gemm<0><<<dim3(27, 392), 256, 0, stream>>>(xb, wbT, Qp, Kp, Vp, nullptr, nullptr);
    k_pool<<<1764, 256, 0, stream>>>(Qp, af);
    k_stageA<<<dim3(7, 128), 256, 0, stream>>>(Kp, Vp, af, b1, part);
    k_reduceA<<<128, 256, 0, stream>>>(part, agv);
    k_stageB<<<dim3(13, 128), 256, 0, stream>>>(Qp, af, agv, b2, out);
    k_conv<<<28224, 256, 0, stream>>>(Vp, out, dwcw, gam, bet, xb /*pre*/);
    k_gemm<1><<<dim3(9, 392), 256, 0, stream>>>(xb /*pre*/, wpT, nullptr, nullptr, nullptr, out, projb);
}